// Round 19
// baseline (108.235 us; speedup 1.0000x reference)
//
#include <hip/hip_runtime.h>
#include <hip/hip_fp16.h>

#define N_NODES 100000
#define N_EDGES 1600000
#define D 64
#define ZROW 100000                        // zero sentinel node index

// ---- bucket geometry (fixed-capacity regions) ----
#define NPB   240
#define NB    417
#define CAP   8192

// ---- partition geometry ----
#define EPB   8192
#define PBLK  ((N_EDGES + EPB - 1) / EPB)  // 196

// ---- sortb+conv launch ----
#define CONVB 782                          // feat-conversion blocks (512 thr)

// ---- agg geometry: full-residency persistent waves ----
#define AGG_BLOCKS 2048
#define NWAVES (AGG_BLOCKS * 4)            // 8192 waves

// ---- ws layout (~33.7 MB; observed ws ~268 MB) ----
#define W3_FF16     0u                            // f16[(N+1)*64]  12.80 MB
#define W3_FF8      12800128u                     // fp8[(N+1)*64]   6.40 MB
#define W3_PACKED   19200256u                     // int[NB*CAP]    13.66 MB
#define W3_GCUR     (W3_PACKED + 4u * NB * CAP)   // 32,864,512
#define W3_NODEOFF  (W3_GCUR + 4u * NB)
#define W3_NODECNT  (W3_NODEOFF + 4u * N_NODES)
#define W3_W16      ((W3_NODECNT + 4u * N_NODES + 15u) & ~15u)
#define W3_NEED     (W3_W16 + 16384u)

typedef __attribute__((ext_vector_type(8))) _Float16 half8;
typedef __attribute__((ext_vector_type(4))) float f32x4;
typedef __attribute__((ext_vector_type(2))) float f32x2;

__device__ inline unsigned int h2bits(__half2 h) { return *(unsigned int*)&h; }
__device__ inline __half2 bits2h(unsigned int u) { return *(__half2*)&u; }
__device__ inline __half2 h2shfl_xor(__half2 x, int mask) {
    int i = *(int*)&x;
    i = __shfl_xor(i, mask);
    return *(__half2*)&i;
}

// ---------------------------------------------------------------------------
// e4m3 encode/decode.  Builtin path on gfx950 (device pass); portable
// software path otherwise (incl. the HOST compile pass, which lacks the
// amdgcn builtins — R18's bug was gating the *launch* on that).
// ---------------------------------------------------------------------------
__device__ inline unsigned int sw_e4m3(float f) {
    unsigned int s = (__float_as_uint(f) >> 24) & 0x80u;
    float a = fabsf(f);
    if (!(a < 448.f)) return s | 0x7Eu;             // clamp to +-448
    if (a < 0.015625f) {                            // < 2^-6: denormal grid 2^-9
        int q = (int)rintf(a * 512.f);              // 0..8 (8 == 2^-6 pattern)
        return s | (unsigned int)q;
    }
    int e; float m = frexpf(a, &e);                 // a = m*2^e, m in [0.5,1)
    int q = (int)rintf(m * 16.f);                   // 8..16
    if (q == 16) { q = 8; e += 1; }
    return s | (unsigned int)((((e - 1) + 7) << 3) | (q - 8));
}

__device__ inline unsigned int enc4(float a, float b, float c, float d) {
#if __has_builtin(__builtin_amdgcn_cvt_pk_fp8_f32)
    int u = __builtin_amdgcn_cvt_pk_fp8_f32(a, b, 0, false);
    u     = __builtin_amdgcn_cvt_pk_fp8_f32(c, d, u, true);
    return (unsigned int)u;
#else
    return sw_e4m3(a) | (sw_e4m3(b) << 8) | (sw_e4m3(c) << 16) | (sw_e4m3(d) << 24);
#endif
}

__device__ inline void dec_acc(__half2 a[8], unsigned int w, int j) {
#if __has_builtin(__builtin_amdgcn_cvt_pk_f32_fp8)
    const f32x2 lo = __builtin_amdgcn_cvt_pk_f32_fp8((int)w, false);
    const f32x2 hi = __builtin_amdgcn_cvt_pk_f32_fp8((int)w, true);
    a[2 * j]     += __floats2half2_rn(lo.x, lo.y);   // e4m3 exact in f16
    a[2 * j + 1] += __floats2half2_rn(hi.x, hi.y);
#else
    const __half2 sc = __floats2half2_rn(256.f, 256.f);
    unsigned int lo = ((w & 0x80u) << 8) | ((w & 0x7Fu) << 7)
                    | ((w & 0x8000u) << 16) | ((w & 0x7F00u) << 15);
    const unsigned int hw = w >> 16;
    unsigned int hi = ((hw & 0x80u) << 8) | ((hw & 0x7Fu) << 7)
                    | ((hw & 0x8000u) << 16) | ((hw & 0x7F00u) << 15);
    a[2 * j]     += bits2h(lo) * sc;                 // bit-place then x2^8
    a[2 * j + 1] += bits2h(hi) * sc;
#endif
}

// ===========================================================================
// 1) Block-chunked partition into fixed per-bucket regions (R16).
// ===========================================================================
__global__ __launch_bounds__(1024) void k_partition(
    const int* __restrict__ src, const int* __restrict__ dst,
    int* __restrict__ gcur, int* __restrict__ packed)
{
    __shared__ int recs[EPB];        // 32 KB
    __shared__ int cnt[NB];
    __shared__ int scn[512];
    __shared__ int pos[NB];
    __shared__ int cur[NB];
    __shared__ int dlt[NB];

    const int bid = blockIdx.x;
    const int t   = threadIdx.x;
    const int e0  = bid * EPB;
    const int nE  = min(EPB, N_EDGES - e0);

    for (int i = t; i < NB; i += 1024) cnt[i] = 0;
    __syncthreads();

    int pk[8], bk[8];
    #pragma unroll
    for (int k = 0; k < 8; ++k) {
        const int i = t + k * 1024;
        if (i < nE) {
            const int d  = dst[e0 + i];
            const int b  = d / NPB;
            const int dl = d - b * NPB;
            pk[k] = src[e0 + i] | (dl << 17);
            bk[k] = b;
            atomicAdd(&cnt[b], 1);
        } else {
            bk[k] = -1;
        }
    }
    __syncthreads();

    if (t < 512) scn[t] = (t < NB) ? cnt[t] : 0;
    __syncthreads();
    for (int o = 1; o < 512; o <<= 1) {
        int x = 0;
        if (t < 512 && t >= o) x = scn[t - o];
        __syncthreads();
        if (t < 512) scn[t] += x;
        __syncthreads();
    }
    if (t < NB) {
        const int v    = cnt[t];
        const int excl = scn[t] - v;
        pos[t] = excl;
        cur[t] = excl;
        dlt[t] = atomicAdd(&gcur[t], v);
    }
    __syncthreads();

    #pragma unroll
    for (int k = 0; k < 8; ++k) {
        if (bk[k] >= 0) {
            const int p = atomicAdd(&cur[bk[k]], 1);
            recs[p] = pk[k];
        }
    }
    __syncthreads();

    const int w    = t >> 6;
    const int lane = t & 63;
    for (int b = w; b < NB; b += 16) {
        const int n = cnt[b];
        const int o = pos[b];
        const int g = b * CAP + dlt[b];
        for (int i = lane; i < n; i += 64)
            packed[g + i] = recs[o + i];
    }
}

// ===========================================================================
// 2) Fused sortb + conversions.  [0,NB): per-bucket CSR sort.
//    [NB,NB+CONVB): feat -> f16 table AND fp8 table.
//    Block NB+CONVB: W->f16 + zero sentinel rows.
// ===========================================================================
__global__ __launch_bounds__(512) void k_sortb_conv(
    const float* __restrict__ feat,
    const float* __restrict__ Ws, const float* __restrict__ Wn,
    unsigned int* __restrict__ ff16, unsigned int* __restrict__ ff8,
    unsigned int* __restrict__ w16,
    const int* __restrict__ gcur,
    int* packed,
    int* __restrict__ node_off, int* __restrict__ node_cnt)
{
    __shared__ int recs[CAP];        // 32 KB
    __shared__ int lcnt[256];
    __shared__ int sc[256];
    __shared__ int lcur[NPB];

    const int bid = blockIdx.x;
    const int t   = threadIdx.x;

    if (bid >= NB) {
        if (bid < NB + CONVB) {
            const int total = N_NODES * D / 8;
            for (int i = (bid - NB) * 512 + t; i < total; i += CONVB * 512) {
                const float4 x = ((const float4*)feat)[i * 2];
                const float4 y = ((const float4*)feat)[i * 2 + 1];
                uint4 o;
                o.x = h2bits(__floats2half2_rn(x.x, x.y));
                o.y = h2bits(__floats2half2_rn(x.z, x.w));
                o.z = h2bits(__floats2half2_rn(y.x, y.y));
                o.w = h2bits(__floats2half2_rn(y.z, y.w));
                ((uint4*)ff16)[i] = o;
                ((uint2*)ff8)[i] = make_uint2(enc4(x.x, x.y, x.z, x.w),
                                              enc4(y.x, y.y, y.z, y.w));
            }
        } else {
            for (int i = t; i < 2048; i += 512) {
                w16[i]        = h2bits(__floats2half2_rn(Ws[2 * i], Ws[2 * i + 1]));
                w16[2048 + i] = h2bits(__floats2half2_rn(Wn[2 * i], Wn[2 * i + 1]));
            }
            if (t < 32) ff16[ZROW * 32 + t] = 0;    // zero sentinel rows
            if (t < 16) ff8[ZROW * 16 + t] = 0;
        }
        return;
    }

    const int bucket = bid;
    const int base   = bucket * CAP;
    int total = gcur[bucket];
    if (total > CAP) total = CAP;

    if (t < 256) lcnt[t] = 0;
    __syncthreads();

    for (int i = t; i < total; i += 512) {
        const int r = packed[base + i];
        recs[i] = r;
        atomicAdd(&lcnt[r >> 17], 1);
    }
    __syncthreads();

    if (t < 256) sc[t] = lcnt[t];
    __syncthreads();
    for (int o = 1; o < 256; o <<= 1) {
        int x = 0;
        if (t < 256 && t >= o) x = sc[t - o];
        __syncthreads();
        if (t < 256) sc[t] += x;
        __syncthreads();
    }

    if (t < NPB) {
        const int excl = sc[t] - lcnt[t];
        lcur[t] = excl;
        const int n = bucket * NPB + t;
        if (n < N_NODES) {
            node_off[n] = base + excl;
            node_cnt[n] = lcnt[t];
        }
    }
    __syncthreads();

    for (int i = t; i < total; i += 512) {
        const int r   = recs[i];
        const int pos = atomicAdd(&lcur[r >> 17], 1);
        packed[base + pos] = r & 0x1FFFF;
    }
}

// ===========================================================================
// 3) FP8 pull aggregation — persistent, pipelined.  One 64B line per row.
//    Wave = 16 edge-slots x 4 chunks (sub=lane>>2, chunk=lane&3).
//    Lane holds 16 columns as 8 half2.  Mean-f16 -> first 128B of out row.
// ===========================================================================
__device__ inline void agg8(__half2 a[8], int p, int m, int sub, int chunk,
                            const unsigned int* __restrict__ ff8)
{
    const int ng = (m + 31) >> 5;              // 32-edge groups
    for (int q = 0; q < ng; ++q) {
        const int e0 = q * 32 + sub;           // sub in [0,16)
        const int s0 = __shfl(p, e0)      & 0x1FFFF;
        const int s1 = __shfl(p, e0 + 16) & 0x1FFFF;
        const uint4 v0 = ((const uint4*)ff8)[(size_t)s0 * 4 + chunk];
        const uint4 v1 = ((const uint4*)ff8)[(size_t)s1 * 4 + chunk];
        dec_acc(a, v0.x, 0); dec_acc(a, v0.y, 1);
        dec_acc(a, v0.z, 2); dec_acc(a, v0.w, 3);
        dec_acc(a, v1.x, 0); dec_acc(a, v1.y, 1);
        dec_acc(a, v1.z, 2); dec_acc(a, v1.w, 3);
    }
}

__global__ __launch_bounds__(256) void k_agg_fp8(
    const unsigned int* __restrict__ ff8,
    const int* __restrict__ node_off,
    const int* __restrict__ node_cnt,
    const int* __restrict__ packed,
    float* __restrict__ out)
{
    const int wid   = blockIdx.x * 4 + (threadIdx.x >> 6);
    const int lane  = threadIdx.x & 63;
    const int sub   = lane >> 2;       // edge slot 0..15
    const int chunk = lane & 3;        // 16B chunk of the 64B row

    int n     = wid;
    int start = node_off[n];
    int deg   = node_cnt[n];
    int p     = (lane < min(deg, 64)) ? packed[start + lane] : ZROW;

    while (true) {
        const int n1 = n + NWAVES;
        int start1 = 0, deg1 = 0, p1 = ZROW;
        if (n1 < N_NODES) {
            start1 = node_off[n1];
            deg1   = node_cnt[n1];
            if (lane < min(deg1, 64)) p1 = packed[start1 + lane];
        }

        __half2 a[8];
        #pragma unroll
        for (int j = 0; j < 8; ++j) a[j] = __floats2half2_rn(0.f, 0.f);

        agg8(a, p, min(deg, 64), sub, chunk, ff8);
        for (int b = 64; b < deg; b += 64) {            // rare (deg > 64)
            const int rem = min(deg - b, 64);
            const int pp  = (lane < rem) ? packed[start + b + lane] : ZROW;
            agg8(a, pp, rem, sub, chunk, ff8);
        }

        #pragma unroll
        for (int mask = 4; mask <= 32; mask <<= 1) {
            #pragma unroll
            for (int j = 0; j < 8; ++j) a[j] += h2shfl_xor(a[j], mask);
        }

        if (sub == 0) {                // lanes 0..3: 16 cols each
            const float inv = 1.0f / (float)((deg > 0) ? deg : 1);
            const __half2 hinv = __floats2half2_rn(inv, inv);
            uint4 o1, o2;
            o1.x = h2bits(a[0] * hinv); o1.y = h2bits(a[1] * hinv);
            o1.z = h2bits(a[2] * hinv); o1.w = h2bits(a[3] * hinv);
            o2.x = h2bits(a[4] * hinv); o2.y = h2bits(a[5] * hinv);
            o2.z = h2bits(a[6] * hinv); o2.w = h2bits(a[7] * hinv);
            ((uint4*)out)[(size_t)n * 16 + chunk * 2]     = o1;
            ((uint4*)out)[(size_t)n * 16 + chunk * 2 + 1] = o2;
        }

        if (n1 >= N_NODES) break;
        n = n1; start = start1; deg = deg1; p = p1;
    }
}

// ===========================================================================
// 4) MFMA f16 dense update (R14: 256 thr = 4 waves x 16-node tile).
// ===========================================================================
__global__ __launch_bounds__(256) void k_update_mfma(
    const unsigned int* __restrict__ ff16,
    const _Float16* __restrict__ w16,     // [2][64][64]: Ws then Wn, K-major
    float* out)
{
    const int wv   = threadIdx.x >> 6;
    const int lane = threadIdx.x & 63;
    const int n0   = blockIdx.x * 64 + wv * 16;
    const int r16  = lane & 15;
    const int g    = lane >> 4;

    half8 bws[4][2], bwn[4][2];
    #pragma unroll
    for (int nt = 0; nt < 4; ++nt) {
        const int c = nt * 16 + r16;
        #pragma unroll
        for (int kt = 0; kt < 2; ++kt) {
            const int k0 = kt * 32 + g * 8;
            bws[nt][kt] = *(const half8*)(w16 + c * 64 + k0);
            bwn[nt][kt] = *(const half8*)(w16 + 4096 + c * 64 + k0);
        }
    }

    const int arow = n0 + r16;
    const int rc   = (arow < N_NODES) ? arow : (N_NODES - 1);

    f32x4 acc[4] = {{0.f,0.f,0.f,0.f}, {0.f,0.f,0.f,0.f},
                    {0.f,0.f,0.f,0.f}, {0.f,0.f,0.f,0.f}};

    #pragma unroll
    for (int kt = 0; kt < 2; ++kt) {
        const int k8 = kt * 4 + g;
        const uint4 af_u = ((const uint4*)ff16)[(size_t)rc * 8 + k8];
        const uint4 am_u = ((const uint4*)out )[(size_t)rc * 16 + k8];
        const half8 af = *(const half8*)&af_u;
        const half8 am = *(const half8*)&am_u;
        #pragma unroll
        for (int nt = 0; nt < 4; ++nt) {
            acc[nt] = __builtin_amdgcn_mfma_f32_16x16x32_f16(af, bws[nt][kt], acc[nt], 0, 0, 0);
            acc[nt] = __builtin_amdgcn_mfma_f32_16x16x32_f16(am, bwn[nt][kt], acc[nt], 0, 0, 0);
        }
    }

    #pragma unroll
    for (int nt = 0; nt < 4; ++nt) {
        #pragma unroll
        for (int r = 0; r < 4; ++r) {
            const int ro = n0 + g * 4 + r;
            if (ro < N_NODES)
                out[(size_t)ro * 64 + nt * 16 + r16] = acc[nt][r];
        }
    }
}

// ===========================================================================
// tier-0 fallback (tiny ws): atomic scatter + readlane update
// ===========================================================================
__global__ __launch_bounds__(256) void sage_scatter(
    const float* __restrict__ feat,
    const int*   __restrict__ src,
    const int*   __restrict__ dst,
    float*       __restrict__ agg,
    float*       __restrict__ deg)
{
    const int gtid = blockIdx.x * blockDim.x + threadIdx.x;
    const int edge = gtid >> 6;
    const int lane = gtid & 63;
    if (edge >= N_EDGES) return;
    const int s = src[edge];
    const int d = dst[edge];
    atomicAdd(&agg[d * D + lane], feat[s * D + lane]);
    if (lane == 0) atomicAdd(&deg[d], 1.0f);
}

#define RL(v, l) __int_as_float(__builtin_amdgcn_readlane(__float_as_int(v), (l)))

__global__ __launch_bounds__(256) void k_update_div(
    const float* __restrict__ feat,
    const float* __restrict__ Ws,
    const float* __restrict__ Wn,
    const float* __restrict__ deg,
    float* out)
{
    const int wid   = (blockIdx.x * 256 + threadIdx.x) >> 6;
    const int lane  = threadIdx.x & 63;
    const int nwave = (gridDim.x * 256) >> 6;

    const float4* Ws4 = (const float4*)Ws;
    const float4* Wn4 = (const float4*)Wn;
    float4 ws[16], wn[16];
    #pragma unroll
    for (int j = 0; j < 16; ++j) {
        ws[j] = Ws4[lane * 16 + j];
        wn[j] = Wn4[lane * 16 + j];
    }

    for (int n = wid; n < N_NODES; n += nwave) {
        const float f = feat[n * D + lane];
        const float a = out[n * D + lane] / fmaxf(deg[n], 1.0f);
        float s0 = 0.f, s1 = 0.f, m0 = 0.f, m1 = 0.f;
        #pragma unroll
        for (int j = 0; j < 16; ++j) {
            const float4 w_s = ws[j];
            const float4 w_n = wn[j];
            s0 = fmaf(RL(f, 4 * j + 0), w_s.x, s0);
            s1 = fmaf(RL(f, 4 * j + 1), w_s.y, s1);
            s0 = fmaf(RL(f, 4 * j + 2), w_s.z, s0);
            s1 = fmaf(RL(f, 4 * j + 3), w_s.w, s1);
            m0 = fmaf(RL(a, 4 * j + 0), w_n.x, m0);
            m1 = fmaf(RL(a, 4 * j + 1), w_n.y, m1);
            m0 = fmaf(RL(a, 4 * j + 2), w_n.z, m0);
            m1 = fmaf(RL(a, 4 * j + 3), w_n.w, m1);
        }
        out[n * D + lane] = (s0 + s1) + (m0 + m1);
    }
}

extern "C" void kernel_launch(void* const* d_in, const int* in_sizes, int n_in,
                              void* d_out, int out_size, void* d_ws, size_t ws_size,
                              hipStream_t stream) {
    const float* feat = (const float*)d_in[0];
    const int*   src  = (const int*)d_in[1];
    const int*   dst  = (const int*)d_in[2];
    const float* Ws   = (const float*)d_in[3];
    const float* Wn   = (const float*)d_in[4];
    float* out = (float*)d_out;
    char*  ws  = (char*)d_ws;

    if (ws_size >= W3_NEED) {
        unsigned int* ff16 = (unsigned int*)(ws + W3_FF16);
        unsigned int* ff8  = (unsigned int*)(ws + W3_FF8);
        int* packed = (int*)(ws + W3_PACKED);
        int* gcur   = (int*)(ws + W3_GCUR);
        int* noff   = (int*)(ws + W3_NODEOFF);
        int* ncnt   = (int*)(ws + W3_NODECNT);
        unsigned int* w16u = (unsigned int*)(ws + W3_W16);

        hipMemsetAsync(gcur, 0, (size_t)NB * sizeof(int), stream);

        k_partition  <<<PBLK, 1024, 0, stream>>>(src, dst, gcur, packed);
        k_sortb_conv <<<NB + CONVB + 1, 512, 0, stream>>>(
            feat, Ws, Wn, ff16, ff8, w16u, gcur, packed, noff, ncnt);
        k_agg_fp8    <<<AGG_BLOCKS, 256, 0, stream>>>(
            ff8, noff, ncnt, packed, out);
        k_update_mfma<<<(N_NODES + 63) / 64, 256, 0, stream>>>(
            ff16, (const _Float16*)w16u, out);
    } else {
        float* deg = (float*)ws;
        hipMemsetAsync(out, 0, (size_t)N_NODES * D * sizeof(float), stream);
        hipMemsetAsync(deg, 0, (size_t)N_NODES * sizeof(float), stream);
        sage_scatter<<<(N_EDGES * 64) / 256, 256, 0, stream>>>(feat, src, dst, out, deg);
        k_update_div<<<1024, 256, 0, stream>>>(feat, Ws, Wn, deg, out);
    }
}

// Round 20
// 92.660 us; speedup vs baseline: 1.1681x; 1.1681x over previous
//
#include <hip/hip_runtime.h>
#include <hip/hip_fp16.h>

#define N_NODES 100000
#define N_EDGES 1600000
#define D 64
#define ZROW 100000                        // zero sentinel node index

// ---- bucket geometry (fixed-capacity regions) ----
#define NPB   240
#define NB    417
#define CAP   8192

// ---- partition geometry ----
#define EPB   8192
#define PBLK  ((N_EDGES + EPB - 1) / EPB)  // 196

// ---- sortb+conv launch ----
#define CONVB 782                          // feat-conversion blocks (512 thr)

// ---- agg geometry: full-residency persistent waves, 2 nodes per wave-iter ----
#define AGG_BLOCKS 2048
#define NWAVES (AGG_BLOCKS * 4)            // 8192 waves

// ---- ws layout (~27.3 MB; observed ws ~268 MB) ----
#define W3_FF16     0u                            // f16[(N+1)*64]  12.80 MB
#define W3_PACKED   12800128u                     // int[NB*CAP]    13.66 MB
#define W3_GCUR     (W3_PACKED + 4u * NB * CAP)
#define W3_NODEOFF  (W3_GCUR + 4u * NB)
#define W3_NODECNT  (W3_NODEOFF + 4u * N_NODES)
#define W3_W16      (W3_NODECNT + 4u * N_NODES)   // f16[2*64*64] = 16 KB
#define W3_NEED     (W3_W16 + 16384u)

typedef __attribute__((ext_vector_type(8))) _Float16 half8;
typedef __attribute__((ext_vector_type(4))) float f32x4;

__device__ inline unsigned int h2bits(__half2 h) { return *(unsigned int*)&h; }
__device__ inline __half2 bits2h(unsigned int u) { return *(__half2*)&u; }
__device__ inline __half2 h2shfl_xor(__half2 x, int mask) {
    int i = *(int*)&x;
    i = __shfl_xor(i, mask);
    return *(__half2*)&i;
}

// ===========================================================================
// 1) Block-chunked partition into fixed per-bucket regions (R16).
// ===========================================================================
__global__ __launch_bounds__(1024) void k_partition(
    const int* __restrict__ src, const int* __restrict__ dst,
    int* __restrict__ gcur, int* __restrict__ packed)
{
    __shared__ int recs[EPB];        // 32 KB
    __shared__ int cnt[NB];
    __shared__ int scn[512];
    __shared__ int pos[NB];
    __shared__ int cur[NB];
    __shared__ int dlt[NB];

    const int bid = blockIdx.x;
    const int t   = threadIdx.x;
    const int e0  = bid * EPB;
    const int nE  = min(EPB, N_EDGES - e0);

    for (int i = t; i < NB; i += 1024) cnt[i] = 0;
    __syncthreads();

    int pk[8], bk[8];
    #pragma unroll
    for (int k = 0; k < 8; ++k) {
        const int i = t + k * 1024;
        if (i < nE) {
            const int d  = dst[e0 + i];
            const int b  = d / NPB;
            const int dl = d - b * NPB;
            pk[k] = src[e0 + i] | (dl << 17);
            bk[k] = b;
            atomicAdd(&cnt[b], 1);
        } else {
            bk[k] = -1;
        }
    }
    __syncthreads();

    if (t < 512) scn[t] = (t < NB) ? cnt[t] : 0;
    __syncthreads();
    for (int o = 1; o < 512; o <<= 1) {
        int x = 0;
        if (t < 512 && t >= o) x = scn[t - o];
        __syncthreads();
        if (t < 512) scn[t] += x;
        __syncthreads();
    }
    if (t < NB) {
        const int v    = cnt[t];
        const int excl = scn[t] - v;
        pos[t] = excl;
        cur[t] = excl;
        dlt[t] = atomicAdd(&gcur[t], v);
    }
    __syncthreads();

    #pragma unroll
    for (int k = 0; k < 8; ++k) {
        if (bk[k] >= 0) {
            const int p = atomicAdd(&cur[bk[k]], 1);
            recs[p] = pk[k];
        }
    }
    __syncthreads();

    const int w    = t >> 6;
    const int lane = t & 63;
    for (int b = w; b < NB; b += 16) {
        const int n = cnt[b];
        const int o = pos[b];
        const int g = b * CAP + dlt[b];
        for (int i = lane; i < n; i += 64)
            packed[g + i] = recs[o + i];
    }
}

// ===========================================================================
// 2) Fused sortb + conversions (R16).  [0,NB): per-bucket CSR sort.
//    [NB,NB+CONVB): feat->f16.  Block NB+CONVB: W->f16 + zero sentinel row.
// ===========================================================================
__global__ __launch_bounds__(512) void k_sortb_conv(
    const float* __restrict__ feat,
    const float* __restrict__ Ws, const float* __restrict__ Wn,
    unsigned int* __restrict__ ff16, unsigned int* __restrict__ w16,
    const int* __restrict__ gcur,
    int* packed,
    int* __restrict__ node_off, int* __restrict__ node_cnt)
{
    __shared__ int recs[CAP];        // 32 KB
    __shared__ int lcnt[256];
    __shared__ int sc[256];
    __shared__ int lcur[NPB];

    const int bid = blockIdx.x;
    const int t   = threadIdx.x;

    if (bid >= NB) {
        if (bid < NB + CONVB) {
            const int total = N_NODES * D / 8;
            for (int i = (bid - NB) * 512 + t; i < total; i += CONVB * 512) {
                const float4 x = ((const float4*)feat)[i * 2];
                const float4 y = ((const float4*)feat)[i * 2 + 1];
                uint4 o;
                o.x = h2bits(__floats2half2_rn(x.x, x.y));
                o.y = h2bits(__floats2half2_rn(x.z, x.w));
                o.z = h2bits(__floats2half2_rn(y.x, y.y));
                o.w = h2bits(__floats2half2_rn(y.z, y.w));
                ((uint4*)ff16)[i] = o;
            }
        } else {
            for (int i = t; i < 2048; i += 512) {
                w16[i]        = h2bits(__floats2half2_rn(Ws[2 * i], Ws[2 * i + 1]));
                w16[2048 + i] = h2bits(__floats2half2_rn(Wn[2 * i], Wn[2 * i + 1]));
            }
            if (t < 32) ff16[ZROW * 32 + t] = 0;    // zero sentinel row
        }
        return;
    }

    const int bucket = bid;
    const int base   = bucket * CAP;
    int total = gcur[bucket];
    if (total > CAP) total = CAP;

    if (t < 256) lcnt[t] = 0;
    __syncthreads();

    for (int i = t; i < total; i += 512) {
        const int r = packed[base + i];
        recs[i] = r;
        atomicAdd(&lcnt[r >> 17], 1);
    }
    __syncthreads();

    if (t < 256) sc[t] = lcnt[t];
    __syncthreads();
    for (int o = 1; o < 256; o <<= 1) {
        int x = 0;
        if (t < 256 && t >= o) x = sc[t - o];
        __syncthreads();
        if (t < 256) sc[t] += x;
        __syncthreads();
    }

    if (t < NPB) {
        const int excl = sc[t] - lcnt[t];
        lcur[t] = excl;
        const int n = bucket * NPB + t;
        if (n < N_NODES) {
            node_off[n] = base + excl;
            node_cnt[n] = lcnt[t];
        }
    }
    __syncthreads();

    for (int i = t; i < total; i += 512) {
        const int r   = recs[i];
        const int pos = atomicAdd(&lcur[r >> 17], 1);
        packed[base + pos] = r & 0x1FFFF;
    }
}

// ===========================================================================
// 3) F16 pull aggregation — persistent, 2-NODE INTERLEAVED.
//    Wave processes node pair (2w, 2w+1); the q-loop issues 4 independent
//    gather wave-loads (A-pair + B-pair) before accumulating -> 2x the
//    outstanding misses of R16.  ZROW padding makes the shorter node's
//    extra gathers hit the L1-hot zero row.  Lanes 0-7 write row A,
//    lanes 8-15 write row B (both sums live in all lanes post-reduce).
// ===========================================================================
__device__ inline void agg_chunk(
    __half2& a0, __half2& a1, __half2& a2, __half2& a3,
    int p, int m, int sub, int chunk, const unsigned int* __restrict__ ff16)
{
    const int npair = (m + 15) >> 4;
    for (int q = 0; q < npair; ++q) {
        const int e0 = q * 16 + sub;
        const int s0 = __shfl(p, e0)     & 0x1FFFF;
        const int s1 = __shfl(p, e0 + 8) & 0x1FFFF;
        const uint4 v0 = ((const uint4*)ff16)[(size_t)s0 * 8 + chunk];
        const uint4 v1 = ((const uint4*)ff16)[(size_t)s1 * 8 + chunk];
        a0 += bits2h(v0.x); a1 += bits2h(v0.y);
        a2 += bits2h(v0.z); a3 += bits2h(v0.w);
        a0 += bits2h(v1.x); a1 += bits2h(v1.y);
        a2 += bits2h(v1.z); a3 += bits2h(v1.w);
    }
}

__global__ __launch_bounds__(256) void k_agg_pair(
    const unsigned int* __restrict__ ff16,
    const int* __restrict__ node_off,
    const int* __restrict__ node_cnt,
    const int* __restrict__ packed,
    float* __restrict__ out)
{
    const int wid   = blockIdx.x * 4 + (threadIdx.x >> 6);
    const int lane  = threadIdx.x & 63;
    const int sub   = lane >> 3;       // edge slot (0..7)
    const int chunk = lane & 7;        // 16B chunk of the 128B row

    int m  = 2 * wid;                  // even; pair (m, m+1).  N_NODES even.
    int sA = node_off[m],     dA = node_cnt[m];
    int sB = node_off[m + 1], dB = node_cnt[m + 1];
    int pA = (lane < min(dA, 64)) ? packed[sA + lane] : ZROW;
    int pB = (lane < min(dB, 64)) ? packed[sB + lane] : ZROW;

    while (true) {
        // ---- prefetch next pair's state (hides under current gathers) ----
        const int m1 = m + 2 * NWAVES;
        int sA1 = 0, dA1 = 0, pA1 = ZROW, sB1 = 0, dB1 = 0, pB1 = ZROW;
        if (m1 < N_NODES) {
            sA1 = node_off[m1];     dA1 = node_cnt[m1];
            sB1 = node_off[m1 + 1]; dB1 = node_cnt[m1 + 1];
            if (lane < min(dA1, 64)) pA1 = packed[sA1 + lane];
            if (lane < min(dB1, 64)) pB1 = packed[sB1 + lane];
        }

        __half2 a0 = __floats2half2_rn(0.f, 0.f);
        __half2 a1 = a0, a2 = a0, a3 = a0;
        __half2 b0 = a0, b1 = a0, b2 = a0, b3 = a0;

        const int mA = min(dA, 64), mB = min(dB, 64);
        const int np = (max(mA, mB) + 15) >> 4;
        for (int q = 0; q < np; ++q) {
            const int e0  = q * 16 + sub;
            const int sa0 = __shfl(pA, e0)     & 0x1FFFF;   // ZROW-padded
            const int sa1 = __shfl(pA, e0 + 8) & 0x1FFFF;
            const int sb0 = __shfl(pB, e0)     & 0x1FFFF;
            const int sb1 = __shfl(pB, e0 + 8) & 0x1FFFF;
            const uint4 vA0 = ((const uint4*)ff16)[(size_t)sa0 * 8 + chunk];
            const uint4 vA1 = ((const uint4*)ff16)[(size_t)sa1 * 8 + chunk];
            const uint4 vB0 = ((const uint4*)ff16)[(size_t)sb0 * 8 + chunk];
            const uint4 vB1 = ((const uint4*)ff16)[(size_t)sb1 * 8 + chunk];
            a0 += bits2h(vA0.x); a1 += bits2h(vA0.y);
            a2 += bits2h(vA0.z); a3 += bits2h(vA0.w);
            a0 += bits2h(vA1.x); a1 += bits2h(vA1.y);
            a2 += bits2h(vA1.z); a3 += bits2h(vA1.w);
            b0 += bits2h(vB0.x); b1 += bits2h(vB0.y);
            b2 += bits2h(vB0.z); b3 += bits2h(vB0.w);
            b0 += bits2h(vB1.x); b1 += bits2h(vB1.y);
            b2 += bits2h(vB1.z); b3 += bits2h(vB1.w);
        }

        // deg > 64 tails (rare)
        for (int bb = 64; bb < dA; bb += 64) {
            const int rem = min(dA - bb, 64);
            const int pp  = (lane < rem) ? packed[sA + bb + lane] : ZROW;
            agg_chunk(a0, a1, a2, a3, pp, rem, sub, chunk, ff16);
        }
        for (int bb = 64; bb < dB; bb += 64) {
            const int rem = min(dB - bb, 64);
            const int pp  = (lane < rem) ? packed[sB + bb + lane] : ZROW;
            agg_chunk(b0, b1, b2, b3, pp, rem, sub, chunk, ff16);
        }

        #pragma unroll
        for (int mask = 8; mask <= 32; mask <<= 1) {
            a0 += h2shfl_xor(a0, mask); a1 += h2shfl_xor(a1, mask);
            a2 += h2shfl_xor(a2, mask); a3 += h2shfl_xor(a3, mask);
            b0 += h2shfl_xor(b0, mask); b1 += h2shfl_xor(b1, mask);
            b2 += h2shfl_xor(b2, mask); b3 += h2shfl_xor(b3, mask);
        }

        if (lane < 8) {                // row A, chunk = lane
            const float inv = 1.0f / (float)((dA > 0) ? dA : 1);
            uint4 mb;
            mb.x = h2bits(__floats2half2_rn(__low2float(a0) * inv, __high2float(a0) * inv));
            mb.y = h2bits(__floats2half2_rn(__low2float(a1) * inv, __high2float(a1) * inv));
            mb.z = h2bits(__floats2half2_rn(__low2float(a2) * inv, __high2float(a2) * inv));
            mb.w = h2bits(__floats2half2_rn(__low2float(a3) * inv, __high2float(a3) * inv));
            ((uint4*)out)[(size_t)m * 16 + lane] = mb;
        } else if (lane < 16) {        // row B, chunk = lane-8
            const float inv = 1.0f / (float)((dB > 0) ? dB : 1);
            uint4 mb;
            mb.x = h2bits(__floats2half2_rn(__low2float(b0) * inv, __high2float(b0) * inv));
            mb.y = h2bits(__floats2half2_rn(__low2float(b1) * inv, __high2float(b1) * inv));
            mb.z = h2bits(__floats2half2_rn(__low2float(b2) * inv, __high2float(b2) * inv));
            mb.w = h2bits(__floats2half2_rn(__low2float(b3) * inv, __high2float(b3) * inv));
            ((uint4*)out)[(size_t)(m + 1) * 16 + (lane - 8)] = mb;
        }

        if (m1 >= N_NODES) break;
        m = m1;
        sA = sA1; dA = dA1; pA = pA1;
        sB = sB1; dB = dB1; pB = pB1;
    }
}

// ===========================================================================
// 4) MFMA f16 dense update (R14: 256 thr = 4 waves x 16-node tile).
// ===========================================================================
__global__ __launch_bounds__(256) void k_update_mfma(
    const unsigned int* __restrict__ ff16,
    const _Float16* __restrict__ w16,     // [2][64][64]: Ws then Wn, K-major
    float* out)
{
    const int wv   = threadIdx.x >> 6;
    const int lane = threadIdx.x & 63;
    const int n0   = blockIdx.x * 64 + wv * 16;
    const int r16  = lane & 15;
    const int g    = lane >> 4;

    half8 bws[4][2], bwn[4][2];
    #pragma unroll
    for (int nt = 0; nt < 4; ++nt) {
        const int c = nt * 16 + r16;
        #pragma unroll
        for (int kt = 0; kt < 2; ++kt) {
            const int k0 = kt * 32 + g * 8;
            bws[nt][kt] = *(const half8*)(w16 + c * 64 + k0);
            bwn[nt][kt] = *(const half8*)(w16 + 4096 + c * 64 + k0);
        }
    }

    const int arow = n0 + r16;
    const int rc   = (arow < N_NODES) ? arow : (N_NODES - 1);

    f32x4 acc[4] = {{0.f,0.f,0.f,0.f}, {0.f,0.f,0.f,0.f},
                    {0.f,0.f,0.f,0.f}, {0.f,0.f,0.f,0.f}};

    #pragma unroll
    for (int kt = 0; kt < 2; ++kt) {
        const int k8 = kt * 4 + g;
        const uint4 af_u = ((const uint4*)ff16)[(size_t)rc * 8 + k8];
        const uint4 am_u = ((const uint4*)out )[(size_t)rc * 16 + k8];
        const half8 af = *(const half8*)&af_u;
        const half8 am = *(const half8*)&am_u;
        #pragma unroll
        for (int nt = 0; nt < 4; ++nt) {
            acc[nt] = __builtin_amdgcn_mfma_f32_16x16x32_f16(af, bws[nt][kt], acc[nt], 0, 0, 0);
            acc[nt] = __builtin_amdgcn_mfma_f32_16x16x32_f16(am, bwn[nt][kt], acc[nt], 0, 0, 0);
        }
    }

    #pragma unroll
    for (int nt = 0; nt < 4; ++nt) {
        #pragma unroll
        for (int r = 0; r < 4; ++r) {
            const int ro = n0 + g * 4 + r;
            if (ro < N_NODES)
                out[(size_t)ro * 64 + nt * 16 + r16] = acc[nt][r];
        }
    }
}

// ===========================================================================
// tier-0 fallback (tiny ws): atomic scatter + readlane update
// ===========================================================================
__global__ __launch_bounds__(256) void sage_scatter(
    const float* __restrict__ feat,
    const int*   __restrict__ src,
    const int*   __restrict__ dst,
    float*       __restrict__ agg,
    float*       __restrict__ deg)
{
    const int gtid = blockIdx.x * blockDim.x + threadIdx.x;
    const int edge = gtid >> 6;
    const int lane = gtid & 63;
    if (edge >= N_EDGES) return;
    const int s = src[edge];
    const int d = dst[edge];
    atomicAdd(&agg[d * D + lane], feat[s * D + lane]);
    if (lane == 0) atomicAdd(&deg[d], 1.0f);
}

#define RL(v, l) __int_as_float(__builtin_amdgcn_readlane(__float_as_int(v), (l)))

__global__ __launch_bounds__(256) void k_update_div(
    const float* __restrict__ feat,
    const float* __restrict__ Ws,
    const float* __restrict__ Wn,
    const float* __restrict__ deg,
    float* out)
{
    const int wid   = (blockIdx.x * 256 + threadIdx.x) >> 6;
    const int lane  = threadIdx.x & 63;
    const int nwave = (gridDim.x * 256) >> 6;

    const float4* Ws4 = (const float4*)Ws;
    const float4* Wn4 = (const float4*)Wn;
    float4 ws[16], wn[16];
    #pragma unroll
    for (int j = 0; j < 16; ++j) {
        ws[j] = Ws4[lane * 16 + j];
        wn[j] = Wn4[lane * 16 + j];
    }

    for (int n = wid; n < N_NODES; n += nwave) {
        const float f = feat[n * D + lane];
        const float a = out[n * D + lane] / fmaxf(deg[n], 1.0f);
        float s0 = 0.f, s1 = 0.f, m0 = 0.f, m1 = 0.f;
        #pragma unroll
        for (int j = 0; j < 16; ++j) {
            const float4 w_s = ws[j];
            const float4 w_n = wn[j];
            s0 = fmaf(RL(f, 4 * j + 0), w_s.x, s0);
            s1 = fmaf(RL(f, 4 * j + 1), w_s.y, s1);
            s0 = fmaf(RL(f, 4 * j + 2), w_s.z, s0);
            s1 = fmaf(RL(f, 4 * j + 3), w_s.w, s1);
            m0 = fmaf(RL(a, 4 * j + 0), w_n.x, m0);
            m1 = fmaf(RL(a, 4 * j + 1), w_n.y, m1);
            m0 = fmaf(RL(a, 4 * j + 2), w_n.z, m0);
            m1 = fmaf(RL(a, 4 * j + 3), w_n.w, m1);
        }
        out[n * D + lane] = (s0 + s1) + (m0 + m1);
    }
}

extern "C" void kernel_launch(void* const* d_in, const int* in_sizes, int n_in,
                              void* d_out, int out_size, void* d_ws, size_t ws_size,
                              hipStream_t stream) {
    const float* feat = (const float*)d_in[0];
    const int*   src  = (const int*)d_in[1];
    const int*   dst  = (const int*)d_in[2];
    const float* Ws   = (const float*)d_in[3];
    const float* Wn   = (const float*)d_in[4];
    float* out = (float*)d_out;
    char*  ws  = (char*)d_ws;

    if (ws_size >= W3_NEED) {
        unsigned int* ff16 = (unsigned int*)(ws + W3_FF16);
        int* packed = (int*)(ws + W3_PACKED);
        int* gcur   = (int*)(ws + W3_GCUR);
        int* noff   = (int*)(ws + W3_NODEOFF);
        int* ncnt   = (int*)(ws + W3_NODECNT);
        unsigned int* w16u = (unsigned int*)(ws + W3_W16);

        hipMemsetAsync(gcur, 0, (size_t)NB * sizeof(int), stream);

        k_partition  <<<PBLK, 1024, 0, stream>>>(src, dst, gcur, packed);
        k_sortb_conv <<<NB + CONVB + 1, 512, 0, stream>>>(
            feat, Ws, Wn, ff16, w16u, gcur, packed, noff, ncnt);
        k_agg_pair   <<<AGG_BLOCKS, 256, 0, stream>>>(
            ff16, noff, ncnt, packed, out);
        k_update_mfma<<<(N_NODES + 63) / 64, 256, 0, stream>>>(
            ff16, (const _Float16*)w16u, out);
    } else {
        float* deg = (float*)ws;
        hipMemsetAsync(out, 0, (size_t)N_NODES * D * sizeof(float), stream);
        hipMemsetAsync(deg, 0, (size_t)N_NODES * sizeof(float), stream);
        sage_scatter<<<(N_EDGES * 64) / 256, 256, 0, stream>>>(feat, src, dst, out, deg);
        k_update_div<<<1024, 256, 0, stream>>>(feat, Ws, Wn, deg, out);
    }
}